// Round 6
// baseline (24.770 us; speedup 1.0000x reference)
//
#include <hip/hip_runtime.h>

#define HH 512
#define WW 512
#define NP 48    // B*C
#define TW 8     // tile width (2 x 4-vec); 64 lanes span the full 512-px row
#define TR 4     // output rows per thread

typedef float f32x4 __attribute__((ext_vector_type(4)));

__device__ __forceinline__ float min3f(float a, float b, float c) {
    return fminf(fminf(a, b), c);
}
__device__ __forceinline__ float max3f(float a, float b, float c) {
    return fmaxf(fmaxf(a, b), c);
}
__device__ __forceinline__ float med3f(float a, float b, float c) {
    return __builtin_amdgcn_fmed3f(a, b, c);  // exact median, finite inputs
}

// Row load with wave-uniform validity branch (rr is uniform across the wave):
// valid rows take 2 coalesced dwordx4 loads + 2 lane-shuffles for the halo;
// out-of-image rows take the all-zero path with no loads and no selects.
__device__ __forceinline__ void load_row(float dst[10], const float* __restrict__ base,
                                         int rr, int c0, int lane) {
    if (rr >= 0 && rr < HH) {
        const float* rp = base + rr * WW + c0;
        f32x4 a = *reinterpret_cast<const f32x4*>(rp);
        f32x4 b = *reinterpret_cast<const f32x4*>(rp + 4);
        dst[1] = a.x; dst[2] = a.y; dst[3] = a.z; dst[4] = a.w;
        dst[5] = b.x; dst[6] = b.y; dst[7] = b.z; dst[8] = b.w;
        float lv = __shfl_up(dst[8], 1, 64);
        float rv = __shfl_down(dst[1], 1, 64);
        dst[0] = (lane > 0) ? lv : 0.f;   // zero pad at image left edge
        dst[9] = (lane < 63) ? rv : 0.f;  // zero pad at image right edge
    } else {
#pragma unroll
        for (int j = 0; j < 10; ++j) dst[j] = 0.f;
    }
}

// One output row: column-sort interleaved with pixel-combine so each sorted
// column triple dies 2 iterations after creation (short register liveness).
__device__ __forceinline__ void step(const float A[10], const float B[10],
                                     const float C[10], float* op) {
    float lo[10], mi[10], hi[10], o[8];
#pragma unroll
    for (int j = 0; j < 10; ++j) {
        lo[j] = min3f(A[j], B[j], C[j]);
        mi[j] = med3f(A[j], B[j], C[j]);
        hi[j] = max3f(A[j], B[j], C[j]);
        if (j >= 2) {
            int p = j - 2;
            o[p] = med3f(max3f(lo[p], lo[p + 1], lo[p + 2]),
                         med3f(mi[p], mi[p + 1], mi[p + 2]),
                         min3f(hi[p], hi[p + 1], hi[p + 2]));
        }
    }
    f32x4 o0 = {o[0], o[1], o[2], o[3]};
    f32x4 o1 = {o[4], o[5], o[6], o[7]};
    *reinterpret_cast<f32x4*>(op) = o0;
    *reinterpret_cast<f32x4*>(op + 4) = o1;
}

__global__ __launch_bounds__(256, 6) void MF_10943576670363_kernel(
    const float* __restrict__ in, float* __restrict__ out) {
    // XCD-chunked bijective swizzle: 1536 blocks, 8 XCDs, 192 blocks/XCD;
    // consecutive ty strips (sharing halo rows) stay on one XCD's L2.
    int bid = blockIdx.x;
    int cpx = gridDim.x >> 3;
    int swz = (bid & 7) * cpx + (bid >> 3);

    int idx = swz * 256 + threadIdx.x;
    int tx = idx & 63;          // W/TW = 64 col tiles == lane id
    int ty = (idx >> 6) & 127;  // H/TR = 128 row strips
    int p  = idx >> 13;         // plane

    int c0 = tx * TW;
    int r0 = ty * TR;
    const float* base = in + (size_t)p * (HH * WW);
    float* obase = out + (size_t)p * (HH * WW);

    // Software-pipelined: 4 rows up-front, prefetch rows 4/5 between steps.
    float rb0[10], rb1[10], rb2[10], rb3[10], rb4[10], rb5[10];
    load_row(rb0, base, r0 - 1, c0, tx);
    load_row(rb1, base, r0 + 0, c0, tx);
    load_row(rb2, base, r0 + 1, c0, tx);
    load_row(rb3, base, r0 + 2, c0, tx);

    step(rb0, rb1, rb2, obase + (r0 + 0) * WW + c0);
    load_row(rb4, base, r0 + 3, c0, tx);
    step(rb1, rb2, rb3, obase + (r0 + 1) * WW + c0);
    load_row(rb5, base, r0 + 4, c0, tx);
    step(rb2, rb3, rb4, obase + (r0 + 2) * WW + c0);
    step(rb3, rb4, rb5, obase + (r0 + 3) * WW + c0);
}

extern "C" void kernel_launch(void* const* d_in, const int* in_sizes, int n_in,
                              void* d_out, int out_size, void* d_ws, size_t ws_size,
                              hipStream_t stream) {
    const float* image = (const float*)d_in[0];
    float* out = (float*)d_out;
    // threads = NP * (HH/TR) * (WW/TW) = 48*128*64 = 393216 -> 1536 blocks
    // = exactly 6 blocks/CU = 24 waves/CU: one fully-resident cohort.
    int total = NP * (HH / TR) * (WW / TW);
    int blocks = total / 256;
    MF_10943576670363_kernel<<<blocks, 256, 0, stream>>>(image, out);
}

// Round 7
// 21.431 us; speedup vs baseline: 1.1558x; 1.1558x over previous
//
#include <hip/hip_runtime.h>

#define HH 512
#define WW 512
#define NP 48    // B*C
#define TR 4     // output rows per thread; 6 input rows loaded up-front

typedef float f32x4 __attribute__((ext_vector_type(4)));

__device__ __forceinline__ float min3f(float a, float b, float c) {
    return fminf(fminf(a, b), c);
}
__device__ __forceinline__ float max3f(float a, float b, float c) {
    return fmaxf(fmaxf(a, b), c);
}
__device__ __forceinline__ float med3f(float a, float b, float c) {
    return __builtin_amdgcn_fmed3f(a, b, c);  // exact median, finite inputs
}

// Dense-layout row load. Lane L owns cols [4L,4L+3] (group A) and
// [256+4L, 256+4L+3] (group B): each dwordx4 instruction is 64 lanes x 16B
// CONTIGUOUS (8 full cache lines), not the stride-32B half-density pattern.
// Halos via shuffles; group-boundary cols 255/256 via broadcast shuffles.
__device__ __forceinline__ void load_row12(float wA[6], float wB[6],
                                           const float* __restrict__ base,
                                           int rr, int lane) {
    if (rr >= 0 && rr < HH) {
        const float* rp = base + rr * WW;
        f32x4 a = *reinterpret_cast<const f32x4*>(rp + lane * 4);
        f32x4 b = *reinterpret_cast<const f32x4*>(rp + 256 + lane * 4);
        wA[1] = a.x; wA[2] = a.y; wA[3] = a.z; wA[4] = a.w;
        wB[1] = b.x; wB[2] = b.y; wB[3] = b.z; wB[4] = b.w;
        float lA = __shfl_up(a.w, 1, 64);    // col 4L-1
        float rA = __shfl_down(a.x, 1, 64);  // col 4L+4 (invalid at lane 63)
        float lB = __shfl_up(b.w, 1, 64);    // col 256+4L-1 (invalid at lane 0)
        float rB = __shfl_down(b.x, 1, 64);  // col 256+4L+4 (invalid at lane 63)
        float aw63 = __shfl(a.w, 63, 64);    // col 255 (for lane 0's wB[0])
        float bx0  = __shfl(b.x, 0, 64);     // col 256 (for lane 63's wA[5])
        wA[0] = (lane == 0)  ? 0.f  : lA;    // image left edge: zero pad
        wA[5] = (lane == 63) ? bx0  : rA;
        wB[0] = (lane == 0)  ? aw63 : lB;
        wB[5] = (lane == 63) ? 0.f  : rB;    // image right edge: zero pad
    } else {
#pragma unroll
        for (int j = 0; j < 6; ++j) { wA[j] = 0.f; wB[j] = 0.f; }
    }
}

// 6-col window -> 4 output px (Smith column-sort + fmed3 combine).
__device__ __forceinline__ void step6(const float A[6], const float B[6],
                                      const float C[6], float o[4]) {
    float lo[6], mi[6], hi[6];
#pragma unroll
    for (int j = 0; j < 6; ++j) {
        lo[j] = min3f(A[j], B[j], C[j]);
        mi[j] = med3f(A[j], B[j], C[j]);
        hi[j] = max3f(A[j], B[j], C[j]);
    }
#pragma unroll
    for (int j = 0; j < 4; ++j) {
        o[j] = med3f(max3f(lo[j], lo[j + 1], lo[j + 2]),
                     med3f(mi[j], mi[j + 1], mi[j + 2]),
                     min3f(hi[j], hi[j + 1], hi[j + 2]));
    }
}

__global__ __launch_bounds__(256) void MF_10943576670363_kernel(
    const float* __restrict__ in, float* __restrict__ out) {
    // XCD-chunked bijective swizzle: 1536 blocks, 8 XCDs, 192 blocks/XCD;
    // consecutive ty strips (sharing halo rows) stay on one XCD's L2.
    int bid = blockIdx.x;
    int cpx = gridDim.x >> 3;
    int swz = (bid & 7) * cpx + (bid >> 3);

    int lane = threadIdx.x & 63;
    int g = swz * 4 + (threadIdx.x >> 6);  // global wave id
    int ty = g & 127;                       // H/TR = 128 row strips
    int p  = g >> 7;                        // plane

    int r0 = ty * TR;
    const float* base = in + (size_t)p * (HH * WW);
    float* obase = out + (size_t)p * (HH * WW);

    // Load ALL 6 input rows up-front (independent, one latency window).
    float rbA[6][6], rbB[6][6];
#pragma unroll
    for (int k = 0; k < 6; ++k) load_row12(rbA[k], rbB[k], base, r0 + k - 1, lane);

#pragma unroll
    for (int i = 0; i < TR; ++i) {
        float oA[4], oB[4];
        step6(rbA[i], rbA[i + 1], rbA[i + 2], oA);
        step6(rbB[i], rbB[i + 1], rbB[i + 2], oB);
        float* op = obase + (r0 + i) * WW;
        f32x4 vA = {oA[0], oA[1], oA[2], oA[3]};
        f32x4 vB = {oB[0], oB[1], oB[2], oB[3]};
        *reinterpret_cast<f32x4*>(op + lane * 4) = vA;         // dense 1KB/instr
        *reinterpret_cast<f32x4*>(op + 256 + lane * 4) = vB;   // dense 1KB/instr
    }
}

extern "C" void kernel_launch(void* const* d_in, const int* in_sizes, int n_in,
                              void* d_out, int out_size, void* d_ws, size_t ws_size,
                              hipStream_t stream) {
    const float* image = (const float*)d_in[0];
    float* out = (float*)d_out;
    // waves = NP * (HH/TR) = 48*128 = 6144 -> 1536 blocks (4 waves each)
    int blocks = NP * (HH / TR) / 4;
    MF_10943576670363_kernel<<<blocks, 256, 0, stream>>>(image, out);
}

// Round 8
// 21.280 us; speedup vs baseline: 1.1640x; 1.0071x over previous
//
#include <hip/hip_runtime.h>

#define HH 512
#define WW 512
#define NP 48    // B*C
#define TR 8     // output rows per thread; 10 input rows, 6-deep register ring

typedef float f32x4 __attribute__((ext_vector_type(4)));

__device__ __forceinline__ float min3f(float a, float b, float c) {
    return fminf(fminf(a, b), c);
}
__device__ __forceinline__ float max3f(float a, float b, float c) {
    return fmaxf(fmaxf(a, b), c);
}
__device__ __forceinline__ float med3f(float a, float b, float c) {
    return __builtin_amdgcn_fmed3f(a, b, c);  // exact median, finite inputs
}

// Dense-layout row load. Lane L owns cols [4L,4L+3] (group A) and
// [256+4L,256+4L+3] (group B): each dwordx4 is 64 lanes x 16B contiguous.
// Halos via lane shuffles; group boundary (cols 255/256) via broadcasts.
// w[0..5] = group A window, w[6..11] = group B window.
__device__ __forceinline__ void load_row12(float w[12], const float* __restrict__ base,
                                           int rr, int lane) {
    if (rr >= 0 && rr < HH) {
        const float* rp = base + rr * WW;
        f32x4 a = *reinterpret_cast<const f32x4*>(rp + lane * 4);
        f32x4 b = *reinterpret_cast<const f32x4*>(rp + 256 + lane * 4);
        w[1] = a.x; w[2] = a.y; w[3] = a.z; w[4] = a.w;
        w[7] = b.x; w[8] = b.y; w[9] = b.z; w[10] = b.w;
        float lA = __shfl_up(a.w, 1, 64);
        float rA = __shfl_down(a.x, 1, 64);
        float lB = __shfl_up(b.w, 1, 64);
        float rB = __shfl_down(b.x, 1, 64);
        float aw63 = __shfl(a.w, 63, 64);   // col 255
        float bx0  = __shfl(b.x, 0, 64);    // col 256
        w[0]  = (lane == 0)  ? 0.f  : lA;   // image left edge
        w[5]  = (lane == 63) ? bx0  : rA;
        w[6]  = (lane == 0)  ? aw63 : lB;
        w[11] = (lane == 63) ? 0.f  : rB;   // image right edge
    } else {
#pragma unroll
        for (int j = 0; j < 12; ++j) w[j] = 0.f;
    }
}

// 6-col window of 3 rows -> 4 output px (Smith column-sort + fmed3 combine).
__device__ __forceinline__ void step6(const float* A, const float* B,
                                      const float* C, float o[4]) {
    float lo[6], mi[6], hi[6];
#pragma unroll
    for (int j = 0; j < 6; ++j) {
        lo[j] = min3f(A[j], B[j], C[j]);
        mi[j] = med3f(A[j], B[j], C[j]);
        hi[j] = max3f(A[j], B[j], C[j]);
    }
#pragma unroll
    for (int j = 0; j < 4; ++j) {
        o[j] = med3f(max3f(lo[j], lo[j + 1], lo[j + 2]),
                     med3f(mi[j], mi[j + 1], mi[j + 2]),
                     min3f(hi[j], hi[j + 1], hi[j + 2]));
    }
}

__global__ __launch_bounds__(256) void MF_10943576670363_kernel(
    const float* __restrict__ in, float* __restrict__ out) {
    // XCD-chunked bijective swizzle: 768 blocks, 8 XCDs, 96 blocks/XCD.
    int bid = blockIdx.x;
    int cpx = gridDim.x >> 3;
    int swz = (bid & 7) * cpx + (bid >> 3);

    int lane = threadIdx.x & 63;
    int g = swz * 4 + (threadIdx.x >> 6);  // global wave id
    int ty = g & 63;                        // H/TR = 64 row strips
    int p  = g >> 6;                        // plane

    int r0 = ty * TR;
    const float* base = in + (size_t)p * (HH * WW);
    float* obase = out + (size_t)p * (HH * WW);

    // 6-deep register ring, statically indexed (fully unrolled loop).
    // rb[k] initially holds row r0-1+k for k=0..4; step i consumes
    // rb[i%6], rb[(i+1)%6], rb[(i+2)%6] and (for i<5) prefetches row
    // r0+i+4 into rb[(i+5)%6], whose old row died at step i-1.
    float rb[6][12];
#pragma unroll
    for (int k = 0; k < 5; ++k) load_row12(rb[k], base, r0 + k - 1, lane);

#pragma unroll
    for (int i = 0; i < TR; ++i) {
        if (i < 5) load_row12(rb[(i + 5) % 6], base, r0 + i + 4, lane);
        float oA[4], oB[4];
        step6(&rb[i % 6][0], &rb[(i + 1) % 6][0], &rb[(i + 2) % 6][0], oA);
        step6(&rb[i % 6][6], &rb[(i + 1) % 6][6], &rb[(i + 2) % 6][6], oB);
        float* op = obase + (r0 + i) * WW;
        f32x4 vA = {oA[0], oA[1], oA[2], oA[3]};
        f32x4 vB = {oB[0], oB[1], oB[2], oB[3]};
        *reinterpret_cast<f32x4*>(op + lane * 4) = vA;
        *reinterpret_cast<f32x4*>(op + 256 + lane * 4) = vB;
    }
}

extern "C" void kernel_launch(void* const* d_in, const int* in_sizes, int n_in,
                              void* d_out, int out_size, void* d_ws, size_t ws_size,
                              hipStream_t stream) {
    const float* image = (const float*)d_in[0];
    float* out = (float*)d_out;
    // waves = NP * (HH/TR) = 48*64 = 3072 -> 768 blocks = 12 waves/CU.
    int blocks = NP * (HH / TR) / 4;
    MF_10943576670363_kernel<<<blocks, 256, 0, stream>>>(image, out);
}